// Round 10
// baseline (54.809 us; speedup 1.0000x reference)
//
#include <hip/hip_runtime.h>
#include <hip/hip_bf16.h>

#define T_TOK 4096
#define HID   150
#define HPAD  160
#define NSPAN 40915
#define MAXW  10
#define NT    10             // 160/16 col tiles

typedef __attribute__((ext_vector_type(8))) _Float16 f16x8;
typedef __attribute__((ext_vector_type(4))) float    f32x4;

static __device__ __forceinline__ f16x8 cvt8(const float* __restrict__ row, int kbase, int K) {
    f16x8 a;
    if (kbase + 8 <= K) {
        float4 v0 = *(const float4*)(row + kbase);
        float4 v1 = *(const float4*)(row + kbase + 4);
        a[0] = (_Float16)v0.x; a[1] = (_Float16)v0.y;
        a[2] = (_Float16)v0.z; a[3] = (_Float16)v0.w;
        a[4] = (_Float16)v1.x; a[5] = (_Float16)v1.y;
        a[6] = (_Float16)v1.z; a[7] = (_Float16)v1.w;
    } else {
#pragma unroll
        for (int e = 0; e < 8; e++)
            a[e] = (_Float16)((kbase + e < K) ? row[kbase + e] : 0.f);
    }
    return a;
}

// ---------------- k_prep: weight frag conversions + width constants (158 blocks)
__global__ __launch_bounds__(256) void k_prep(
    const float* __restrict__ aW1, const float* __restrict__ sW1,
    const float* __restrict__ aW2, const float* __restrict__ sW2,
    const float* __restrict__ wt, const float* __restrict__ sb1,
    _Float16* __restrict__ fW1, _Float16* __restrict__ fA1,
    _Float16* __restrict__ fB1, _Float16* __restrict__ fE1,
    _Float16* __restrict__ fA2, _Float16* __restrict__ fW2,
    float* __restrict__ wc)
{
    const int b = blockIdx.x;
    const int w = threadIdx.x >> 6, l = threadIdx.x & 63;

    if (b < 148) {
        int tw = b * 4 + w;
        if (tw >= 590) return;
        const float* src; int srcK, off; _Float16* d;
        if      (tw < 130) { src = aW1;             srcK = 400; off = 0;   d = fW1; }
        else if (tw < 260) { src = sW1;             srcK = 400; off = 130; d = fA1; }
        else if (tw < 390) { src = sW1 + 400 * HID; srcK = 400; off = 260; d = fB1; }
        else if (tw < 490) { src = sW1 + 800 * HID; srcK = 300; off = 390; d = fE1; }
        else if (tw < 540) { src = aW2;             srcK = 150; off = 490; d = fA2; }
        else               { src = sW2;             srcK = 150; off = 540; d = fW2; }
        int tb = tw - off;
        int kt = tb / NT, nt = tb - kt * NT;
        int n = nt * 16 + (l & 15);
        int kbase = kt * 32 + (l >> 4) * 8;
        f16x8 hv;
#pragma unroll
        for (int e = 0; e < 8; e++) {
            int k = kbase + e;
            float f = (k < srcK && n < HID) ? src[(size_t)k * HID + n] : 0.f;
            hv[e] = (_Float16)f;
        }
        *(f16x8*)(d + ((size_t)tb * 64 + l) * 8) = hv;
    } else {
        int n = b - 147;             // 1..10
        int c = threadIdx.x;
        if (c >= HPAD) return;
        float s = 0.f;
        if (c < HID) {
            const int dt[11] = {0, 1, 2, 3, 4, 4, 4, 4, 5, 5, 5};
            const float* ww = wt + dt[n] * 20;
            s = sb1[c];
#pragma unroll
            for (int j = 0; j < 20; j++) s = fmaf(ww[j], sW1[(1100 + j) * HID + c], s);
        }
        wc[(n - 1) * HPAD + c] = s;
    }
}

// ---------------- k_main: 512 blocks, each owns 8 starts (t0 = bid*8) -> 80 spans.
// Everything block-local: project token tile (32 rows) -> A/B/E LDS tiles + H1 frags,
// attn layer2+3 -> local scores, softmax, pool from LDS -> h1 frags, final GEMM -> out.
__global__ __launch_bounds__(256, 2) void k_main(
    const float* __restrict__ states, const float* __restrict__ embeds,
    const _Float16* __restrict__ fW1, const _Float16* __restrict__ fA1,
    const _Float16* __restrict__ fB1, const _Float16* __restrict__ fE1,
    const _Float16* __restrict__ fA2, const _Float16* __restrict__ fW2,
    const float* __restrict__ ab1, const float* __restrict__ ab2,
    const float* __restrict__ aW3, const float* __restrict__ ab3,
    const float* __restrict__ wcbuf, const float* __restrict__ sb2,
    const float* __restrict__ sW3, const float* __restrict__ sb3,
    float* __restrict__ out)
{
    // LDS layout (71.8 KB -> 2 blocks/CU):
    // [0, 26624)      Sf: 26 state A-frag tiles (phase A) / hh: 25 span frag tiles (D/E)
    // [26624, 36864)  Atile[32][160] f16
    // [36864, 47104)  Btile[32][160] f16
    // [47104, 57344)  Etile[32][160] f16
    // [57344, 67584)  hh1: H1 frags (A->B)
    // [67584, 70784)  wg[80][10] f32
    // [70784, 70912)  scl[32] f32
    // [70912, 71552)  red[2][5][16] f32
    // [71552, 71808)  redB[4][16] f32
    __shared__ alignas(16) char smem[71808];
    _Float16* Sf    = (_Float16*)(smem);
    _Float16* Atile = (_Float16*)(smem + 26624);
    _Float16* Btile = (_Float16*)(smem + 36864);
    _Float16* Etile = (_Float16*)(smem + 47104);
    _Float16* hh1   = (_Float16*)(smem + 57344);
    float*    wg    = (float*)   (smem + 67584);
    float*    scl   = (float*)   (smem + 70784);
    float*    red   = (float*)   (smem + 70912);
    float*    redB  = (float*)   (smem + 71552);

    const int tid  = threadIdx.x;
    const int w    = tid >> 6, l = tid & 63;
    const int mtl  = w >> 1, nh = w & 1, m15 = l & 15;
    const int koff = (l >> 4) * 8;
    const int t0   = blockIdx.x * 8;

    // ---- phase A0: states rows -> S-frags (26 tiles), waves cooperate
    for (int ft = w; ft < 26; ft += 4) {
        int mt2 = ft / 13, kt = ft - mt2 * 13;
        int row = min(t0 + mt2 * 16 + m15, T_TOK - 1);
        f16x8 a = cvt8(states + (size_t)row * 400, kt * 32 + koff, 400);
        *(f16x8*)(Sf + ((size_t)ft * 64 + l) * 8) = a;
    }
    __syncthreads();

    // ---- phase A1: three GEMMs (H1 | A | B) from S-frags
    for (int g = 0; g < 3; ++g) {
        const f16x8* pB = (const f16x8*)(g == 0 ? fW1 : (g == 1 ? fA1 : fB1));
        f32x4 acc[5];
#pragma unroll
        for (int c = 0; c < 5; c++) acc[c] = (f32x4){0.f, 0.f, 0.f, 0.f};
#pragma unroll
        for (int kt = 0; kt < 13; ++kt) {
            f16x8 a = *(const f16x8*)(Sf + (((mtl * 13 + kt) * 64) + l) * 8);
#pragma unroll
            for (int c = 0; c < 5; c++) {
                f16x8 bv = pB[(size_t)(kt * NT + nh * 5 + c) * 64 + l];
                acc[c] = __builtin_amdgcn_mfma_f32_16x16x32_f16(a, bv, acc[c], 0, 0, 0);
            }
        }
        if (g == 0) {
            // relu(H1 + ab1) -> hh1 frags
#pragma unroll
            for (int c = 0; c < 5; c++) {
                int u = nh * 5 + c;
                int col = u * 16 + m15;
                float bb = (col < HID) ? ab1[col] : 0.f;
                int kt2 = u >> 1;
                int gg = (u & 1) * 2 + (m15 >> 3);
                int e = m15 & 7;
#pragma unroll
                for (int r = 0; r < 4; r++) {
                    int rloc = (l >> 4) * 4 + r;
                    float v = fmaxf(acc[c][r] + bb, 0.f);
                    hh1[((mtl * 5 + kt2) * 64 + gg * 16 + rloc) * 8 + e] = (_Float16)v;
                }
            }
        } else {
            _Float16* Tt = (g == 1) ? Atile : Btile;
#pragma unroll
            for (int c = 0; c < 5; c++) {
                int col = (nh * 5 + c) * 16 + m15;
#pragma unroll
                for (int r = 0; r < 4; r++) {
                    int rr = mtl * 16 + (l >> 4) * 4 + r;
                    Tt[rr * HPAD + col] = (_Float16)acc[c][r];
                }
            }
        }
    }
    // ---- phase A2: E projection (embeds, KT=10, inline cvt)
    {
        f32x4 acc[5];
#pragma unroll
        for (int c = 0; c < 5; c++) acc[c] = (f32x4){0.f, 0.f, 0.f, 0.f};
        int row = min(t0 + mtl * 16 + m15, T_TOK - 1);
        const float* arow = embeds + (size_t)row * 300;
#pragma unroll 2
        for (int kt = 0; kt < 10; ++kt) {
            f16x8 a = cvt8(arow, kt * 32 + koff, 300);
#pragma unroll
            for (int c = 0; c < 5; c++) {
                f16x8 bv = ((const f16x8*)fE1)[(size_t)(kt * NT + nh * 5 + c) * 64 + l];
                acc[c] = __builtin_amdgcn_mfma_f32_16x16x32_f16(a, bv, acc[c], 0, 0, 0);
            }
        }
#pragma unroll
        for (int c = 0; c < 5; c++) {
            int col = (nh * 5 + c) * 16 + m15;
#pragma unroll
            for (int r = 0; r < 4; r++) {
                int rr = mtl * 16 + (l >> 4) * 4 + r;
                Etile[rr * HPAD + col] = (_Float16)acc[c][r];
            }
        }
    }
    __syncthreads();

    // ---- phase B: attn layer2 (K=160) vs fA2 + relu + dot(aW3) -> scl[32]
    {
        f32x4 acc2[5];
#pragma unroll
        for (int c = 0; c < 5; c++) acc2[c] = (f32x4){0.f, 0.f, 0.f, 0.f};
        const f16x8* pH = (const f16x8*)hh1;
        const f16x8* pB2 = (const f16x8*)fA2;
#pragma unroll
        for (int kt = 0; kt < 5; ++kt) {
            f16x8 a = pH[(mtl * 5 + kt) * 64 + l];
#pragma unroll
            for (int c = 0; c < 5; c++) {
                f16x8 bv = pB2[(size_t)(kt * NT + nh * 5 + c) * 64 + l];
                acc2[c] = __builtin_amdgcn_mfma_f32_16x16x32_f16(a, bv, acc2[c], 0, 0, 0);
            }
        }
        float p[4] = {0.f, 0.f, 0.f, 0.f};
#pragma unroll
        for (int c = 0; c < 5; c++) {
            int col = (nh * 5 + c) * 16 + m15;
            float bb = (col < HID) ? ab2[col] : 0.f;
            float wv = (col < HID) ? aW3[col] : 0.f;
#pragma unroll
            for (int r = 0; r < 4; r++) {
                float v = fmaxf(acc2[c][r] + bb, 0.f);
                p[r] = fmaf(v, wv, p[r]);
            }
        }
#pragma unroll
        for (int off = 1; off < 16; off <<= 1)
#pragma unroll
            for (int r = 0; r < 4; r++) p[r] += __shfl_xor(p[r], off);
        if (m15 == 0)
#pragma unroll
            for (int r = 0; r < 4; r++) redB[w * 16 + (l >> 4) * 4 + r] = p[r];
        __syncthreads();
        if (tid < 32)
            scl[tid] = redB[((tid >> 4) * 2 + 0) * 16 + (tid & 15)] +
                       redB[((tid >> 4) * 2 + 1) * 16 + (tid & 15)] + ab3[0];
    }
    __syncthreads();

    // ---- phase C: softmax weights for 80 local spans (ls = ni*8 + si)
    if (tid < 80) {
        int ni = tid >> 3, si = tid & 7;
        int n = ni + 1;
        float sc[MAXW]; float mx = -1e30f;
#pragma unroll
        for (int i = 0; i < MAXW; i++) {
            sc[i] = (i < n) ? scl[si + i] : -1e30f;
            mx = fmaxf(mx, sc[i]);
        }
        float ssum = 0.f;
#pragma unroll
        for (int i = 0; i < MAXW; i++) { sc[i] = __expf(sc[i] - mx); ssum += sc[i]; }
        float inv = 1.f / ssum;
#pragma unroll
        for (int i = 0; i < MAXW; i++) wg[tid * 10 + i] = (i < n) ? sc[i] * inv : 0.f;
    }
    __syncthreads();

    // ---- phase D: pool from LDS tiles -> span h1 frags (80 spans x 20 qcols = 1600 tasks)
#pragma unroll
    for (int it = 0; it < 7; ++it) {
        int task = it * 256 + tid;
        if (task < 1600) {
            int sl = task / 20, q = task - sl * 20;
            int ni = sl >> 3, si = sl & 7;
            int d0 = q * 8;
            f16x8 a8 = *(const f16x8*)(Atile + si * HPAD + d0);
            f16x8 b8 = *(const f16x8*)(Btile + (si + ni) * HPAD + d0);
            float4 w4a = *(const float4*)(wcbuf + ni * HPAD + d0);
            float4 w4b = *(const float4*)(wcbuf + ni * HPAD + d0 + 4);
            float v[8];
            v[0] = (float)a8[0] + (float)b8[0] + w4a.x;
            v[1] = (float)a8[1] + (float)b8[1] + w4a.y;
            v[2] = (float)a8[2] + (float)b8[2] + w4a.z;
            v[3] = (float)a8[3] + (float)b8[3] + w4a.w;
            v[4] = (float)a8[4] + (float)b8[4] + w4b.x;
            v[5] = (float)a8[5] + (float)b8[5] + w4b.y;
            v[6] = (float)a8[6] + (float)b8[6] + w4b.z;
            v[7] = (float)a8[7] + (float)b8[7] + w4b.w;
#pragma unroll
            for (int i = 0; i < MAXW; i++) {
                f16x8 e8 = *(const f16x8*)(Etile + (si + i) * HPAD + d0);
                float aa = wg[sl * 10 + i];
#pragma unroll
                for (int e = 0; e < 8; e++) v[e] = fmaf(aa, (float)e8[e], v[e]);
            }
            f16x8 hv;
#pragma unroll
            for (int e = 0; e < 8; e++) hv[e] = (_Float16)fmaxf(v[e], 0.f);
            int mti = sl >> 4, rr = sl & 15;
            int kt = q >> 2, gg = q & 3;
            *(f16x8*)(Sf + (((mti * 5 + kt) * 64 + gg * 16 + rr) * 8)) = hv;  // Sf reused as hh
        }
    }
    __syncthreads();

    // ---- phase E: final GEMM (M=80, 5 mtiles) vs fW2 + relu + dot(sW3)
    {
        const f16x8* pW2 = (const f16x8*)fW2;
        for (int mti = (w >> 1); mti < 5; mti += 2) {
            f32x4 acc[5];
#pragma unroll
            for (int c = 0; c < 5; c++) acc[c] = (f32x4){0.f, 0.f, 0.f, 0.f};
#pragma unroll
            for (int kt = 0; kt < 5; ++kt) {
                f16x8 a = *(const f16x8*)(Sf + (((mti * 5 + kt) * 64) + l) * 8);
#pragma unroll
                for (int c = 0; c < 5; c++) {
                    f16x8 bv = pW2[(size_t)(kt * NT + nh * 5 + c) * 64 + l];
                    acc[c] = __builtin_amdgcn_mfma_f32_16x16x32_f16(a, bv, acc[c], 0, 0, 0);
                }
            }
            float p[4] = {0.f, 0.f, 0.f, 0.f};
#pragma unroll
            for (int c = 0; c < 5; c++) {
                int col = (nh * 5 + c) * 16 + m15;
                float bb = (col < HID) ? sb2[col] : 0.f;
                float wv = (col < HID) ? sW3[col] : 0.f;
#pragma unroll
                for (int r = 0; r < 4; r++) {
                    float v = fmaxf(acc[c][r] + bb, 0.f);
                    p[r] = fmaf(v, wv, p[r]);
                }
            }
#pragma unroll
            for (int off = 1; off < 16; off <<= 1)
#pragma unroll
                for (int r = 0; r < 4; r++) p[r] += __shfl_xor(p[r], off);
            if (m15 == 0)
#pragma unroll
                for (int r = 0; r < 4; r++)
                    red[(nh * 5 + mti) * 16 + (l >> 4) * 4 + r] = p[r];
        }
    }
    __syncthreads();

    // ---- write out valid spans
    if (tid < 80) {
        int mti = tid >> 4, rr = tid & 15;
        float val = red[(0 * 5 + mti) * 16 + rr] + red[(1 * 5 + mti) * 16 + rr] + sb3[0];
        int ni = tid >> 3, si = tid & 7;
        int start = t0 + si, n = ni + 1;
        if (start + n <= T_TOK) {
            int base = ni * (T_TOK + 1) - (ni * (ni + 1)) / 2;
            out[base + start] = val;
        }
    }
}

extern "C" void kernel_launch(void* const* d_in, const int* in_sizes, int n_in,
                              void* d_out, int out_size, void* d_ws, size_t ws_size,
                              hipStream_t stream) {
    const float* embeds = (const float*)d_in[0];
    const float* states = (const float*)d_in[1];
    const float* aW1 = (const float*)d_in[2];
    const float* ab1 = (const float*)d_in[3];
    const float* aW2 = (const float*)d_in[4];
    const float* ab2 = (const float*)d_in[5];
    const float* aW3 = (const float*)d_in[6];
    const float* ab3 = (const float*)d_in[7];
    const float* wt  = (const float*)d_in[8];
    const float* sW1 = (const float*)d_in[9];
    const float* sb1 = (const float*)d_in[10];
    const float* sW2 = (const float*)d_in[11];
    const float* sb2 = (const float*)d_in[12];
    const float* sW3 = (const float*)d_in[13];
    const float* sb3 = (const float*)d_in[14];
    float* out = (float*)d_out;

    char* W = (char*)d_ws;
    _Float16* fW1  = (_Float16*)(W + 0);        // 416*160*2 = 133120
    _Float16* fA1  = (_Float16*)(W + 133120);
    _Float16* fB1  = (_Float16*)(W + 266240);
    _Float16* fE1  = (_Float16*)(W + 399360);   // 320*160*2 = 102400
    _Float16* fA2  = (_Float16*)(W + 501760);   // 160*160*2 = 51200
    _Float16* fW2  = (_Float16*)(W + 552960);
    float*    wcbuf= (float*)   (W + 604160);   // 10*160*4 = 6400

    // weight frags + width constants (158 blocks)
    k_prep<<<158, 256, 0, stream>>>(aW1, sW1, aW2, sW2, wt, sb1,
                                    fW1, fA1, fB1, fE1, fA2, fW2, wcbuf);
    // everything else, block-local (512 blocks)
    k_main<<<512, 256, 0, stream>>>(states, embeds,
        fW1, fA1, fB1, fE1, fA2, fW2,
        ab1, ab2, aW3, ab3, wcbuf, sb2, sW3, sb3, out);
}

// Round 11
// 37.644 us; speedup vs baseline: 1.4560x; 1.4560x over previous
//
#include <hip/hip_runtime.h>
#include <hip/hip_bf16.h>

#define T_TOK 4096
#define HID   150
#define HPAD  160
#define NSPAN 40915
#define MAXW  10
#define NT    10             // 160/16 col tiles

typedef __attribute__((ext_vector_type(8))) _Float16 f16x8;
typedef __attribute__((ext_vector_type(4))) float    f32x4;

static __device__ __forceinline__ f16x8 cvt8(const float* __restrict__ row, int kbase, int K) {
    f16x8 a;
    if (kbase + 8 <= K) {
        float4 v0 = *(const float4*)(row + kbase);
        float4 v1 = *(const float4*)(row + kbase + 4);
        a[0] = (_Float16)v0.x; a[1] = (_Float16)v0.y;
        a[2] = (_Float16)v0.z; a[3] = (_Float16)v0.w;
        a[4] = (_Float16)v1.x; a[5] = (_Float16)v1.y;
        a[6] = (_Float16)v1.z; a[7] = (_Float16)v1.w;
    } else {
#pragma unroll
        for (int e = 0; e < 8; e++)
            a[e] = (_Float16)((kbase + e < K) ? row[kbase + e] : 0.f);
    }
    return a;
}

// ---------------- k_prep: weight frag conversions + width constants (158 blocks)
__global__ __launch_bounds__(256) void k_prep(
    const float* __restrict__ aW1, const float* __restrict__ sW1,
    const float* __restrict__ aW2, const float* __restrict__ sW2,
    const float* __restrict__ wt, const float* __restrict__ sb1,
    _Float16* __restrict__ fW1, _Float16* __restrict__ fA1,
    _Float16* __restrict__ fB1, _Float16* __restrict__ fE1,
    _Float16* __restrict__ fA2, _Float16* __restrict__ fW2,
    float* __restrict__ wc)
{
    const int b = blockIdx.x;
    const int w = threadIdx.x >> 6, l = threadIdx.x & 63;

    if (b < 148) {
        int tw = b * 4 + w;
        if (tw >= 590) return;
        const float* src; int srcK, off; _Float16* d;
        if      (tw < 130) { src = aW1;             srcK = 400; off = 0;   d = fW1; }
        else if (tw < 260) { src = sW1;             srcK = 400; off = 130; d = fA1; }
        else if (tw < 390) { src = sW1 + 400 * HID; srcK = 400; off = 260; d = fB1; }
        else if (tw < 490) { src = sW1 + 800 * HID; srcK = 300; off = 390; d = fE1; }
        else if (tw < 540) { src = aW2;             srcK = 150; off = 490; d = fA2; }
        else               { src = sW2;             srcK = 150; off = 540; d = fW2; }
        int tb = tw - off;
        int kt = tb / NT, nt = tb - kt * NT;
        int n = nt * 16 + (l & 15);
        int kbase = kt * 32 + (l >> 4) * 8;
        f16x8 hv;
#pragma unroll
        for (int e = 0; e < 8; e++) {
            int k = kbase + e;
            float f = (k < srcK && n < HID) ? src[(size_t)k * HID + n] : 0.f;
            hv[e] = (_Float16)f;
        }
        *(f16x8*)(d + ((size_t)tb * 64 + l) * 8) = hv;
    } else {
        int n = b - 147;             // 1..10
        int c = threadIdx.x;
        if (c >= HPAD) return;
        float s = 0.f;
        if (c < HID) {
            const int dt[11] = {0, 1, 2, 3, 4, 4, 4, 4, 5, 5, 5};
            const float* ww = wt + dt[n] * 20;
            s = sb1[c];
#pragma unroll
            for (int j = 0; j < 20; j++) s = fmaf(ww[j], sW1[(1100 + j) * HID + c], s);
        }
        wc[(n - 1) * HPAD + c] = s;
    }
}

// ---------------- k_proj: grid (128, 4) x 512 threads (8 waves).
// wave = (mtl, nh, kh): kh splits the K range; partials combined via LDS.
// y=0: states @ aW1 -> relu -> LDS frags -> @ aW2 -> relu -> dot(aW3) -> scores
// y=1,2,3: states/embeds projections -> Abuf/Bbuf/Ebuf (fp16)
__global__ __launch_bounds__(512) void k_proj(
    const float* __restrict__ states, const float* __restrict__ embeds,
    const _Float16* __restrict__ fW1, const _Float16* __restrict__ fA1,
    const _Float16* __restrict__ fB1, const _Float16* __restrict__ fE1,
    const _Float16* __restrict__ fA2,
    const float* __restrict__ ab1, const float* __restrict__ ab2,
    const float* __restrict__ aW3, const float* __restrict__ ab3,
    _Float16* __restrict__ Abuf, _Float16* __restrict__ Bbuf,
    _Float16* __restrict__ Ebuf, float* __restrict__ scores)
{
    __shared__ float smP[256 * 21];             // kh=1 partials (pad 21 vs 20: no bank conflict)
    __shared__ alignas(16) _Float16 hh[5120];   // H1 frags (y=0)
    __shared__ float red[4][16];

    const float* Asrc; int lda, srcK, KT; const _Float16* Bf; _Float16* C = nullptr;
    switch (blockIdx.y) {
        case 0: Asrc = states; lda = 400; srcK = 400; KT = 13; Bf = fW1; break;
        case 1: Asrc = states; lda = 400; srcK = 400; KT = 13; Bf = fA1; C = Abuf; break;
        case 2: Asrc = states; lda = 400; srcK = 400; KT = 13; Bf = fB1; C = Bbuf; break;
        default:Asrc = embeds; lda = 300; srcK = 300; KT = 10; Bf = fE1; C = Ebuf; break;
    }
    const int tid = threadIdx.x;
    const int w   = tid >> 6, l = tid & 63;
    const int mtl = w >> 2;            // 0/1
    const int nh  = (w >> 1) & 1;      // 0/1
    const int kh  = w & 1;             // 0/1 : K-split half
    const int mt  = blockIdx.x * 2 + mtl;
    const int m15 = l & 15;
    const int koff = (l >> 4) * 8;
    const float* arow = Asrc + (size_t)(mt * 16 + m15) * lda;
    const f16x8* pB = (const f16x8*)Bf;
    const int pid = (mtl * 2 + nh) * 64 + l;   // 0..255

    f32x4 acc[5];
#pragma unroll
    for (int c = 0; c < 5; c++) acc[c] = (f32x4){0.f, 0.f, 0.f, 0.f};

    // K-split GEMM: KT=13 -> [0,7)/[7,13); KT=10 -> [0,5)/[5,10). Constant bounds for unroll.
    if (KT == 13) {
        if (kh == 0) {
#pragma unroll
            for (int kt = 0; kt < 7; ++kt) {
                f16x8 a = cvt8(arow, kt * 32 + koff, 400);
#pragma unroll
                for (int c = 0; c < 5; c++) {
                    f16x8 bv = pB[(size_t)(kt * NT + nh * 5 + c) * 64 + l];
                    acc[c] = __builtin_amdgcn_mfma_f32_16x16x32_f16(a, bv, acc[c], 0, 0, 0);
                }
            }
        } else {
#pragma unroll
            for (int kt = 7; kt < 13; ++kt) {
                f16x8 a = cvt8(arow, kt * 32 + koff, 400);
#pragma unroll
                for (int c = 0; c < 5; c++) {
                    f16x8 bv = pB[(size_t)(kt * NT + nh * 5 + c) * 64 + l];
                    acc[c] = __builtin_amdgcn_mfma_f32_16x16x32_f16(a, bv, acc[c], 0, 0, 0);
                }
            }
        }
    } else {
        if (kh == 0) {
#pragma unroll
            for (int kt = 0; kt < 5; ++kt) {
                f16x8 a = cvt8(arow, kt * 32 + koff, 300);
#pragma unroll
                for (int c = 0; c < 5; c++) {
                    f16x8 bv = pB[(size_t)(kt * NT + nh * 5 + c) * 64 + l];
                    acc[c] = __builtin_amdgcn_mfma_f32_16x16x32_f16(a, bv, acc[c], 0, 0, 0);
                }
            }
        } else {
#pragma unroll
            for (int kt = 5; kt < 10; ++kt) {
                f16x8 a = cvt8(arow, kt * 32 + koff, 300);
#pragma unroll
                for (int c = 0; c < 5; c++) {
                    f16x8 bv = pB[(size_t)(kt * NT + nh * 5 + c) * 64 + l];
                    acc[c] = __builtin_amdgcn_mfma_f32_16x16x32_f16(a, bv, acc[c], 0, 0, 0);
                }
            }
        }
    }

    // combine kh=1 partials into kh=0
    if (kh == 1) {
#pragma unroll
        for (int c = 0; c < 5; c++)
#pragma unroll
            for (int r = 0; r < 4; r++) smP[pid * 21 + c * 4 + r] = acc[c][r];
    }
    __syncthreads();
    if (kh == 0) {
#pragma unroll
        for (int c = 0; c < 5; c++)
#pragma unroll
            for (int r = 0; r < 4; r++) acc[c][r] += smP[pid * 21 + c * 4 + r];
    }

    if (blockIdx.y != 0) {
        if (kh == 0) {
            const int m0 = mt * 16;
#pragma unroll
            for (int c = 0; c < 5; c++) {
                int col = (nh * 5 + c) * 16 + m15;
#pragma unroll
                for (int r = 0; r < 4; r++) {
                    int row = m0 + (l >> 4) * 4 + r;
                    C[(size_t)row * HPAD + col] = (_Float16)acc[c][r];
                }
            }
        }
        return;
    }

    // ---- fused attention (y=0): relu(H1 + ab1) -> LDS frags (kh=0 waves hold the sums)
    if (kh == 0) {
#pragma unroll
        for (int c = 0; c < 5; c++) {
            int u   = nh * 5 + c;
            int col = u * 16 + m15;
            float bb = (col < HID) ? ab1[col] : 0.f;
            int kt2 = u >> 1;
            int g  = (u & 1) * 2 + (m15 >> 3);
            int e  = m15 & 7;
#pragma unroll
            for (int r = 0; r < 4; r++) {
                int rloc = (l >> 4) * 4 + r;
                float v = fmaxf(acc[c][r] + bb, 0.f);
                hh[((mtl * 5 + kt2) * 64 + g * 16 + rloc) * 8 + e] = (_Float16)v;
            }
        }
    }
    __syncthreads();

    // ---- layer2 GEMM (K=160) from LDS frags vs fA2, + relu + dot(aW3) (kh=0 waves)
    if (kh == 0) {
        const f16x8* pH = (const f16x8*)hh;
        const f16x8* pB2 = (const f16x8*)fA2;
        f32x4 acc2[5];
#pragma unroll
        for (int c = 0; c < 5; c++) acc2[c] = (f32x4){0.f, 0.f, 0.f, 0.f};
#pragma unroll
        for (int kt = 0; kt < 5; ++kt) {
            f16x8 a = pH[(mtl * 5 + kt) * 64 + l];
#pragma unroll
            for (int c = 0; c < 5; c++) {
                f16x8 bv = pB2[(size_t)(kt * NT + nh * 5 + c) * 64 + l];
                acc2[c] = __builtin_amdgcn_mfma_f32_16x16x32_f16(a, bv, acc2[c], 0, 0, 0);
            }
        }
        float p[4] = {0.f, 0.f, 0.f, 0.f};
#pragma unroll
        for (int c = 0; c < 5; c++) {
            int col = (nh * 5 + c) * 16 + m15;
            float bb = (col < HID) ? ab2[col] : 0.f;
            float wv = (col < HID) ? aW3[col] : 0.f;
#pragma unroll
            for (int r = 0; r < 4; r++) {
                float v = fmaxf(acc2[c][r] + bb, 0.f);
                p[r] = fmaf(v, wv, p[r]);
            }
        }
#pragma unroll
        for (int off = 1; off < 16; off <<= 1)
#pragma unroll
            for (int r = 0; r < 4; r++) p[r] += __shfl_xor(p[r], off);
        if (m15 == 0)
#pragma unroll
            for (int r = 0; r < 4; r++) red[mtl * 2 + nh][(l >> 4) * 4 + r] = p[r];
    }
    __syncthreads();
    if (tid < 32) {
        scores[blockIdx.x * 32 + tid] =
            red[(tid >> 4) * 2 + 0][tid & 15] + red[(tid >> 4) * 2 + 1][tid & 15] + ab3[0];
    }
}

// ---------------- k_spanfinal: 1279 blocks x 32 spans.
// phase0: wave-parallel softmax (8 lanes/span); phase1: h1 tile -> LDS frags
// (E-loop MAXW-unrolled); phase2: GEMM vs fW2 + relu + dot(sW3) -> out
__global__ __launch_bounds__(256) void k_spanfinal(
    const float* __restrict__ scores, const _Float16* __restrict__ Abuf,
    const _Float16* __restrict__ Bbuf, const _Float16* __restrict__ Ebuf,
    const float* __restrict__ wc,
    const _Float16* __restrict__ fW2,
    const float* __restrict__ sb2, const float* __restrict__ sW3,
    const float* __restrict__ sb3, float* __restrict__ out)
{
    __shared__ alignas(16) _Float16 hh[5120];
    __shared__ float wg[32][10];
    __shared__ int   stI[32], nnI[32];
    __shared__ float red[4][16];

    const int tid = threadIdx.x;
    const int s0  = blockIdx.x * 32;

    // phase 0: softmax, 8 lanes per span (all 256 threads active)
    {
        int sl = tid >> 3, k = tid & 7;
        int span = s0 + sl;
        int n = 1, start = 0;
        if (span < NSPAN) {
            int base = 0;
#pragma unroll
            for (int i = 1; i <= MAXW; i++) {
                int ww = T_TOK - i + 1;
                if (span < base + ww) { n = i; break; }
                base += ww;
            }
            start = span - base;
        }
        float x0 = (k < n)     ? scores[start + k]     : -1e30f;
        float x1 = (k + 8 < n) ? scores[start + k + 8] : -1e30f;
        float m = fmaxf(x0, x1);
        m = fmaxf(m, __shfl_xor(m, 1));
        m = fmaxf(m, __shfl_xor(m, 2));
        m = fmaxf(m, __shfl_xor(m, 4));
        float e0 = __expf(x0 - m), e1 = __expf(x1 - m);
        float s = e0 + e1;
        s += __shfl_xor(s, 1);
        s += __shfl_xor(s, 2);
        s += __shfl_xor(s, 4);
        float inv = 1.f / s;
        wg[sl][k] = e0 * inv;
        if (k < 2) wg[sl][k + 8] = e1 * inv;
        if (k == 0) { stI[sl] = start; nnI[sl] = n; }
    }
    __syncthreads();

    // phase 1: 640 tasks (32 spans x 20 8-col groups), 3 strided iterations
#pragma unroll
    for (int it = 0; it < 3; ++it) {
        int task = it * 256 + tid;
        if (task < 640) {
            int sl = task / 20;
            int q  = task - sl * 20;
            int start = stI[sl];
            int nn = nnI[sl];
            int d0 = q * 8;
            f16x8 a8 = *(const f16x8*)(Abuf + (size_t)start * HPAD + d0);
            f16x8 b8 = *(const f16x8*)(Bbuf + (size_t)(start + nn - 1) * HPAD + d0);
            const float* wr = wc + (nn - 1) * HPAD + d0;
            float v[8];
#pragma unroll
            for (int e = 0; e < 8; e++) v[e] = (float)a8[e] + (float)b8[e] + wr[e];
#pragma unroll
            for (int i = 0; i < MAXW; i++) {
                int ridx = min(start + i, T_TOK - 1);
                f16x8 e8 = *(const f16x8*)(Ebuf + (size_t)ridx * HPAD + d0);
                float aa = wg[sl][i];
#pragma unroll
                for (int e = 0; e < 8; e++) v[e] = fmaf(aa, (float)e8[e], v[e]);
            }
            f16x8 hv;
#pragma unroll
            for (int e = 0; e < 8; e++) hv[e] = (_Float16)fmaxf(v[e], 0.f);
            int mtl = sl >> 4, smr = sl & 15;
            int kt = q >> 2, gg = q & 3;
            *(f16x8*)(hh + ((mtl * 5 + kt) * 64 + gg * 16 + smr) * 8) = hv;
        }
    }
    __syncthreads();

    // phase 2: GEMM (K=160) vs fW2 + relu + dot(sW3) -> out
    const int w = tid >> 6, l = tid & 63;
    const int mtl = w >> 1, nh = w & 1;
    const int m15 = l & 15;
    const f16x8* pH = (const f16x8*)hh;
    const f16x8* pB = (const f16x8*)fW2;
    f32x4 acc[5];
#pragma unroll
    for (int c = 0; c < 5; c++) acc[c] = (f32x4){0.f, 0.f, 0.f, 0.f};
#pragma unroll
    for (int kt = 0; kt < 5; ++kt) {
        f16x8 a = pH[(mtl * 5 + kt) * 64 + l];
#pragma unroll
        for (int c = 0; c < 5; c++) {
            f16x8 bv = pB[(size_t)(kt * NT + nh * 5 + c) * 64 + l];
            acc[c] = __builtin_amdgcn_mfma_f32_16x16x32_f16(a, bv, acc[c], 0, 0, 0);
        }
    }
    float p[4] = {0.f, 0.f, 0.f, 0.f};
#pragma unroll
    for (int c = 0; c < 5; c++) {
        int col = (nh * 5 + c) * 16 + m15;
        float bb = (col < HID) ? sb2[col] : 0.f;
        float wv = (col < HID) ? sW3[col] : 0.f;
#pragma unroll
        for (int r = 0; r < 4; r++) {
            float v = fmaxf(acc[c][r] + bb, 0.f);
            p[r] = fmaf(v, wv, p[r]);
        }
    }
#pragma unroll
    for (int off = 1; off < 16; off <<= 1)
#pragma unroll
        for (int r = 0; r < 4; r++) p[r] += __shfl_xor(p[r], off);
    if (m15 == 0)
#pragma unroll
        for (int r = 0; r < 4; r++) red[w][(l >> 4) * 4 + r] = p[r];
    __syncthreads();
    if (tid < 32) {
        int row = s0 + tid;
        if (row < NSPAN)
            out[row] = red[(tid >> 4) * 2 + 0][tid & 15] +
                       red[(tid >> 4) * 2 + 1][tid & 15] + sb3[0];
    }
}

extern "C" void kernel_launch(void* const* d_in, const int* in_sizes, int n_in,
                              void* d_out, int out_size, void* d_ws, size_t ws_size,
                              hipStream_t stream) {
    const float* embeds = (const float*)d_in[0];
    const float* states = (const float*)d_in[1];
    const float* aW1 = (const float*)d_in[2];
    const float* ab1 = (const float*)d_in[3];
    const float* aW2 = (const float*)d_in[4];
    const float* ab2 = (const float*)d_in[5];
    const float* aW3 = (const float*)d_in[6];
    const float* ab3 = (const float*)d_in[7];
    const float* wt  = (const float*)d_in[8];
    const float* sW1 = (const float*)d_in[9];
    const float* sb1 = (const float*)d_in[10];
    const float* sW2 = (const float*)d_in[11];
    const float* sb2 = (const float*)d_in[12];
    const float* sW3 = (const float*)d_in[13];
    const float* sb3 = (const float*)d_in[14];
    float* out = (float*)d_out;

    char* W = (char*)d_ws;
    _Float16* Abuf = (_Float16*)(W + 0);          // 4096*160*2 = 1310720
    _Float16* Bbuf = (_Float16*)(W + 1310720);
    _Float16* Ebuf = (_Float16*)(W + 2621440);
    float* scores  = (float*)(W + 3932160);       // 16384
    float* wcbuf   = (float*)(W + 3948544);       // 6400
    _Float16* fW1  = (_Float16*)(W + 3954944);    // 416*160*2 = 133120
    _Float16* fA1  = (_Float16*)(W + 4088064);
    _Float16* fB1  = (_Float16*)(W + 4221184);
    _Float16* fE1  = (_Float16*)(W + 4354304);    // 320*160*2 = 102400
    _Float16* fA2  = (_Float16*)(W + 4456704);    // 160*160*2 = 51200
    _Float16* fW2  = (_Float16*)(W + 4507904);

    // weight frags + width constants (158 blocks)
    k_prep<<<158, 256, 0, stream>>>(aW1, sW1, aW2, sW2, wt, sb1,
                                    fW1, fA1, fB1, fE1, fA2, fW2, wcbuf);
    // projections + fused attention -> scores (512 blocks x 8 waves, split-K)
    k_proj<<<dim3(128, 4), 512, 0, stream>>>(states, embeds,
        fW1, fA1, fB1, fE1, fA2, ab1, ab2, aW3, ab3, Abuf, Bbuf, Ebuf, scores);
    // spans + final MLP -> out (1279 blocks)
    k_spanfinal<<<1279, 256, 0, stream>>>(scores, Abuf, Bbuf, Ebuf, wcbuf,
        fW2, sb2, sW3, sb3, out);
}